// Round 1
// baseline (261.414 us; speedup 1.0000x reference)
//
#include <hip/hip_runtime.h>
#include <hip/hip_bf16.h>

typedef __attribute__((ext_vector_type(4))) float f32x4;
typedef __attribute__((ext_vector_type(8))) short bf16x8;

__device__ __forceinline__ void gload_lds16(const void* g, void* l) {
  __builtin_amdgcn_global_load_lds(
      (const __attribute__((address_space(1))) void*)g,
      (__attribute__((address_space(3))) void*)l, 16, 0, 0);
}

__device__ __forceinline__ unsigned short f2bf(float f) {
  union { float f; unsigned u; } x; x.f = f;
  unsigned r = x.u + 0x7fffu + ((x.u >> 16) & 1u);
  return (unsigned short)(r >> 16);
}

__device__ __forceinline__ float bf2f(unsigned short s) {
  union { unsigned u; float f; } x; x.u = (unsigned)s << 16;
  return x.f;
}

// ---------------------------------------------------------------------------
// GEMM: C[M][N] = alpha * A[M][K] @ Bt[N][K]^T (+ bias[N]); A,Bt bf16,
// C bf16 or f32. 128x128 tile, 4 waves, BK=32, global_load_lds staging.
// ---------------------------------------------------------------------------
template<bool OUT_F32, bool HAS_BIAS>
__global__ __launch_bounds__(256, 2)
void gemm_bt_kernel(const unsigned short* __restrict__ A,
                    const unsigned short* __restrict__ Bt,
                    const float* __restrict__ bias,
                    void* __restrict__ Cout,
                    int M, int N, int K, float alpha,
                    long sA, long sB, long sC)
{
  __shared__ __attribute__((aligned(16))) unsigned short As[128 * 32];
  __shared__ __attribute__((aligned(16))) unsigned short Bs[128 * 32];

  const int tid  = threadIdx.x;
  const int wave = tid >> 6, lane = tid & 63;
  const int z = blockIdx.z;
  A  += (size_t)z * sA;
  Bt += (size_t)z * sB;

  const int m0 = blockIdx.y * 128;
  const int n0 = blockIdx.x * 128;

  f32x4 acc[4][4] = {};

  const int wr = wave >> 1, wc = wave & 1;
  const int fr = lane & 15, fq = lane >> 4;

  // staging map: 8 chunks of 1KB (512 bf16); chunk i: rows i*16..i*16+15
  const int si0 = wave * 2;
  const int sr  = lane >> 2;          // sub-row within chunk
  const int sce = (lane & 3) * 8;     // element offset within row (16B)

  for (int k0 = 0; k0 < K; k0 += 32) {
#pragma unroll
    for (int c = 0; c < 2; ++c) {
      const int i = si0 + c;
      const int r = i * 16 + sr;
      gload_lds16(A  + (size_t)(m0 + r) * K + k0 + sce, As + i * 512 + lane * 8);
      gload_lds16(Bt + (size_t)(n0 + r) * K + k0 + sce, Bs + i * 512 + lane * 8);
    }
    __syncthreads();

    bf16x8 af[4], bg[4];
#pragma unroll
    for (int m = 0; m < 4; ++m)
      af[m] = *(const bf16x8*)(As + (wr * 64 + m * 16 + fr) * 32 + fq * 8);
#pragma unroll
    for (int n = 0; n < 4; ++n)
      bg[n] = *(const bf16x8*)(Bs + (wc * 64 + n * 16 + fr) * 32 + fq * 8);

#pragma unroll
    for (int m = 0; m < 4; ++m)
#pragma unroll
      for (int n = 0; n < 4; ++n)
        acc[m][n] = __builtin_amdgcn_mfma_f32_16x16x32_bf16(af[m], bg[n], acc[m][n], 0, 0, 0);

    __syncthreads();
  }

  // epilogue: C row = m0 + wr*64 + m*16 + fq*4 + j, col = n0 + wc*64 + n*16 + fr
#pragma unroll
  for (int n = 0; n < 4; ++n) {
    const int col = n0 + wc * 64 + n * 16 + fr;
    const float bv = HAS_BIAS ? bias[col] : 0.f;
#pragma unroll
    for (int m = 0; m < 4; ++m) {
      const int rbase = m0 + wr * 64 + m * 16 + fq * 4;
#pragma unroll
      for (int j = 0; j < 4; ++j) {
        const float v = acc[m][n][j] * alpha + bv;
        const size_t off = (size_t)z * sC + (size_t)(rbase + j) * N + col;
        if (OUT_F32) ((float*)Cout)[off] = v;
        else         ((unsigned short*)Cout)[off] = f2bf(v);
      }
    }
  }
}

// ---------------------------------------------------------------------------
// x fp32 -> bf16 (8 elements/thread)
// ---------------------------------------------------------------------------
__global__ __launch_bounds__(256)
void convert_x_kernel(const float* __restrict__ x, unsigned short* __restrict__ xb)
{
  const int idx = (blockIdx.x * 256 + threadIdx.x) * 8;
  const float4 a = *(const float4*)(x + idx);
  const float4 b = *(const float4*)(x + idx + 4);
  unsigned u0 = (unsigned)f2bf(a.x) | ((unsigned)f2bf(a.y) << 16);
  unsigned u1 = (unsigned)f2bf(a.z) | ((unsigned)f2bf(a.w) << 16);
  unsigned u2 = (unsigned)f2bf(b.x) | ((unsigned)f2bf(b.y) << 16);
  unsigned u3 = (unsigned)f2bf(b.z) | ((unsigned)f2bf(b.w) << 16);
  uint4 o; o.x = u0; o.y = u1; o.z = u2; o.w = u3;
  *(uint4*)(xb + idx) = o;
}

// ---------------------------------------------------------------------------
// W fp32 [1024][1024] (k-major) -> Wt bf16 [1024][1024] (n-major), 4 weights
// ---------------------------------------------------------------------------
__global__ __launch_bounds__(256)
void transpose_w_kernel(const float* __restrict__ Wa, const float* __restrict__ Wb,
                        const float* __restrict__ Wc, const float* __restrict__ Wd,
                        unsigned short* __restrict__ Wt)
{
  __shared__ float t[64][65];
  const float* W = (blockIdx.z == 0) ? Wa : (blockIdx.z == 1) ? Wb
                 : (blockIdx.z == 2) ? Wc : Wd;
  unsigned short* out = Wt + (size_t)blockIdx.z * 1024 * 1024;
  const int k0 = blockIdx.y * 64;
  const int n0 = blockIdx.x * 64;
  const int tx = threadIdx.x & 63, ty = threadIdx.x >> 6;
#pragma unroll
  for (int r = ty; r < 64; r += 4)
    t[r][tx] = W[(size_t)(k0 + r) * 1024 + n0 + tx];
  __syncthreads();
#pragma unroll
  for (int r = ty; r < 64; r += 4)
    out[(size_t)(n0 + r) * 1024 + k0 + tx] = f2bf(t[tx][r]);
}

// ---------------------------------------------------------------------------
// V bf16 [b][2048][1024] -> Vt bf16 [b][1024][2048]
// ---------------------------------------------------------------------------
__global__ __launch_bounds__(256)
void transpose_v_kernel(const unsigned short* __restrict__ V, unsigned short* __restrict__ Vt)
{
  __shared__ unsigned short t[64][65];
  const unsigned short* Vb = V  + (size_t)blockIdx.z * 2048 * 1024;
  unsigned short*      Vtb = Vt + (size_t)blockIdx.z * 1024 * 2048;
  const int t0 = blockIdx.y * 64;   // V row (t)
  const int e0 = blockIdx.x * 64;   // V col (e)
  const int tx = threadIdx.x & 63, ty = threadIdx.x >> 6;
#pragma unroll
  for (int r = ty; r < 64; r += 4)
    t[r][tx] = Vb[(size_t)(t0 + r) * 1024 + e0 + tx];
  __syncthreads();
#pragma unroll
  for (int r = ty; r < 64; r += 4)
    Vtb[(size_t)(e0 + r) * 2048 + t0 + tx] = t[tx][r];
}

// ---------------------------------------------------------------------------
// row softmax, in place, bf16 rows of 2048 (one block per row)
// ---------------------------------------------------------------------------
__global__ __launch_bounds__(256)
void softmax_kernel(unsigned short* __restrict__ S)
{
  __shared__ float red[8];
  unsigned short* r = S + (size_t)blockIdx.x * 2048;
  const int tid = threadIdx.x, lane = tid & 63, wave = tid >> 6;

  uint4 pk = *(const uint4*)(r + tid * 8);
  const unsigned short* ps = (const unsigned short*)&pk;
  float v[8];
#pragma unroll
  for (int j = 0; j < 8; ++j) v[j] = bf2f(ps[j]);

  float mx = v[0];
#pragma unroll
  for (int j = 1; j < 8; ++j) mx = fmaxf(mx, v[j]);
#pragma unroll
  for (int o = 32; o; o >>= 1) mx = fmaxf(mx, __shfl_xor(mx, o));
  if (lane == 0) red[wave] = mx;
  __syncthreads();
  mx = fmaxf(fmaxf(red[0], red[1]), fmaxf(red[2], red[3]));

  float s = 0.f;
#pragma unroll
  for (int j = 0; j < 8; ++j) { v[j] = __expf(v[j] - mx); s += v[j]; }
#pragma unroll
  for (int o = 32; o; o >>= 1) s += __shfl_xor(s, o);
  if (lane == 0) red[4 + wave] = s;
  __syncthreads();
  const float inv = 1.f / (red[4] + red[5] + red[6] + red[7]);

  unsigned short o8[8];
#pragma unroll
  for (int j = 0; j < 8; ++j) o8[j] = f2bf(v[j] * inv);
  *(uint4*)(r + tid * 8) = *(const uint4*)o8;
}

// ---------------------------------------------------------------------------
extern "C" void kernel_launch(void* const* d_in, const int* in_sizes, int n_in,
                              void* d_out, int out_size, void* d_ws, size_t ws_size,
                              hipStream_t stream)
{
  const float* x  = (const float*)d_in[0];
  const float* W1 = (const float*)d_in[1];
  const float* b1 = (const float*)d_in[2];
  const float* W2 = (const float*)d_in[3];
  const float* b2 = (const float*)d_in[4];
  const float* W3 = (const float*)d_in[5];
  const float* b3 = (const float*)d_in[6];
  const float* W4 = (const float*)d_in[7];
  const float* b4 = (const float*)d_in[8];

  char* ws = (char*)d_ws;
  const size_t MB = 1024 * 1024;
  unsigned short* xb = (unsigned short*)(ws);             // 16MB (later Vt)
  unsigned short* Wt = (unsigned short*)(ws + 16 * MB);   // 8MB: Wt[4][1024][1024]
  unsigned short* Q  = (unsigned short*)(ws + 24 * MB);   // 16MB (later O)
  unsigned short* Kb = (unsigned short*)(ws + 40 * MB);   // 16MB
  unsigned short* V  = (unsigned short*)(ws + 56 * MB);   // 16MB
  unsigned short* S  = (unsigned short*)(ws + 72 * MB);   // 32MB [4][2048][2048]
  unsigned short* Vt = xb;                                // alias: x dead after QKV
  unsigned short* O  = Q;                                 // alias: Q dead after scores

  // 1. convert x to bf16
  convert_x_kernel<<<4096, 256, 0, stream>>>(x, xb);
  // 2. transpose+convert weights
  transpose_w_kernel<<<dim3(16, 16, 4), 256, 0, stream>>>(W1, W2, W3, W4, Wt);

  // 3. Q/K/V projections: [8192,1024] = xb @ WtX^T + bX  (bf16 out)
  dim3 gqkv(1024 / 128, 8192 / 128, 1);
  gemm_bt_kernel<false, true><<<gqkv, 256, 0, stream>>>(xb, Wt + 0 * 1048576, b1, Q,  8192, 1024, 1024, 1.f, 0, 0, 0);
  gemm_bt_kernel<false, true><<<gqkv, 256, 0, stream>>>(xb, Wt + 1 * 1048576, b2, Kb, 8192, 1024, 1024, 1.f, 0, 0, 0);
  gemm_bt_kernel<false, true><<<gqkv, 256, 0, stream>>>(xb, Wt + 2 * 1048576, b3, V,  8192, 1024, 1024, 1.f, 0, 0, 0);

  // 4. V -> Vt per batch
  transpose_v_kernel<<<dim3(16, 32, 4), 256, 0, stream>>>(V, Vt);

  // 5. scores: S[b] = (Q[b] @ K[b]^T) / 32  (bf16 out)
  dim3 gsc(2048 / 128, 2048 / 128, 4);
  gemm_bt_kernel<false, false><<<gsc, 256, 0, stream>>>(Q, Kb, nullptr, S, 2048, 2048, 1024, 0.03125f,
                                                        2048L * 1024, 2048L * 1024, 2048L * 2048);
  // 6. softmax rows, in place
  softmax_kernel<<<8192, 256, 0, stream>>>(S);

  // 7. O[b] = P[b] @ V[b]  (Bt = Vt[b] as [1024][2048])
  dim3 gpv(1024 / 128, 2048 / 128, 4);
  gemm_bt_kernel<false, false><<<gpv, 256, 0, stream>>>(S, Vt, nullptr, O, 2048, 1024, 2048, 1.f,
                                                        2048L * 2048, 1024L * 2048, 2048L * 1024);

  // 8. out = O @ Wt4^T + b4  (fp32 out)
  dim3 gfin(1024 / 128, 8192 / 128, 1);
  gemm_bt_kernel<true, true><<<gfin, 256, 0, stream>>>(O, Wt + 3 * 1048576, b4, d_out, 8192, 1024, 1024, 1.f, 0, 0, 0);
}

// Round 2
// 223.588 us; speedup vs baseline: 1.1692x; 1.1692x over previous
//
#include <hip/hip_runtime.h>
#include <hip/hip_bf16.h>

typedef __attribute__((ext_vector_type(4))) float f32x4;
typedef __attribute__((ext_vector_type(8))) short bf16x8;

__device__ __forceinline__ void gload_lds16(const void* g, void* l) {
  __builtin_amdgcn_global_load_lds(
      (const __attribute__((address_space(1))) void*)g,
      (__attribute__((address_space(3))) void*)l, 16, 0, 0);
}

__device__ __forceinline__ unsigned short f2bf(float f) {
  union { float f; unsigned u; } x; x.f = f;
  unsigned r = x.u + 0x7fffu + ((x.u >> 16) & 1u);
  return (unsigned short)(r >> 16);
}

__device__ __forceinline__ float bf2f(unsigned short s) {
  union { unsigned u; float f; } x; x.u = (unsigned)s << 16;
  return x.f;
}

// ---------------------------------------------------------------------------
// GEMM: C[M][N] = alpha * A[M][K] @ Bt[N][K]^T (+ bias); A,Bt bf16.
// BIAS_MODE: 0 = none, 1 = bias[col], 2 = bias[row].
// 128x128 tile, 4 waves, BK=32, global_load_lds staging, XCD-chunked swizzle.
// ---------------------------------------------------------------------------
template<int BIAS_MODE, bool OUT_F32>
__global__ __launch_bounds__(256, 2)
void gemm_bt_kernel(const unsigned short* __restrict__ A,
                    const unsigned short* __restrict__ Bt,
                    const float* __restrict__ bias,
                    void* __restrict__ Cout,
                    int N, int K, int lda, int ldb, int ldc, float alpha,
                    long sA, long sB, long sC)
{
  __shared__ __attribute__((aligned(16))) unsigned short As[128 * 32];
  __shared__ __attribute__((aligned(16))) unsigned short Bs[128 * 32];

  // bijective XCD-chunked swizzle (m204): contiguous grid chunk per XCD
  const int gx = gridDim.x, gy = gridDim.y;
  const int lid = blockIdx.x + gx * (blockIdx.y + gy * blockIdx.z);
  const int nwg = gx * gy * gridDim.z;
  const int q = nwg >> 3, r = nwg & 7;
  const int xcd = lid & 7, idx = lid >> 3;
  const int nl = (xcd < r ? xcd * (q + 1) : r * (q + 1) + (xcd - r) * q) + idx;
  const int bx = nl % gx, by = (nl / gx) % gy, bz = nl / (gx * gy);

  const int tid  = threadIdx.x;
  const int wave = tid >> 6, lane = tid & 63;
  A  += (size_t)bz * sA;
  Bt += (size_t)bz * sB;

  const int m0 = by * 128;
  const int n0 = bx * 128;

  f32x4 acc[4][4] = {};

  const int wr = wave >> 1, wc = wave & 1;
  const int fr = lane & 15, fq = lane >> 4;

  // staging map: 8 chunks of 1KB (16 rows x 32 cols bf16) per matrix
  const int si0 = wave * 2;
  const int sr  = lane >> 2;          // sub-row within chunk
  const int sce = (lane & 3) * 8;     // element offset within row (16B)

  for (int k0 = 0; k0 < K; k0 += 32) {
#pragma unroll
    for (int c = 0; c < 2; ++c) {
      const int i = si0 + c;
      const int rr = i * 16 + sr;
      gload_lds16(A  + (size_t)(m0 + rr) * lda + k0 + sce, As + i * 512 + lane * 8);
      gload_lds16(Bt + (size_t)(n0 + rr) * ldb + k0 + sce, Bs + i * 512 + lane * 8);
    }
    __syncthreads();

    bf16x8 af[4], bg[4];
#pragma unroll
    for (int m = 0; m < 4; ++m)
      af[m] = *(const bf16x8*)(As + (wr * 64 + m * 16 + fr) * 32 + fq * 8);
#pragma unroll
    for (int n = 0; n < 4; ++n)
      bg[n] = *(const bf16x8*)(Bs + (wc * 64 + n * 16 + fr) * 32 + fq * 8);

#pragma unroll
    for (int m = 0; m < 4; ++m)
#pragma unroll
      for (int n = 0; n < 4; ++n)
        acc[m][n] = __builtin_amdgcn_mfma_f32_16x16x32_bf16(af[m], bg[n], acc[m][n], 0, 0, 0);

    __syncthreads();
  }

  // epilogue: C row = m0 + wr*64 + m*16 + fq*4 + j, col = n0 + wc*64 + n*16 + fr
#pragma unroll
  for (int n = 0; n < 4; ++n) {
    const int col = n0 + wc * 64 + n * 16 + fr;
    const float bvc = (BIAS_MODE == 1) ? bias[col] : 0.f;
#pragma unroll
    for (int m = 0; m < 4; ++m) {
      const int rbase = m0 + wr * 64 + m * 16 + fq * 4;
#pragma unroll
      for (int j = 0; j < 4; ++j) {
        float v = acc[m][n][j] * alpha + bvc;
        if (BIAS_MODE == 2) v += bias[rbase + j];
        const size_t off = (size_t)bz * sC + (size_t)(rbase + j) * ldc + col;
        if (OUT_F32) ((float*)Cout)[off] = v;
        else         ((unsigned short*)Cout)[off] = f2bf(v);
      }
    }
  }
}

// ---------------------------------------------------------------------------
// x fp32 -> bf16 (8 elements/thread)
// ---------------------------------------------------------------------------
__global__ __launch_bounds__(256)
void convert_x_kernel(const float* __restrict__ x, unsigned short* __restrict__ xb)
{
  const int idx = (blockIdx.x * 256 + threadIdx.x) * 8;
  const float4 a = *(const float4*)(x + idx);
  const float4 b = *(const float4*)(x + idx + 4);
  unsigned u0 = (unsigned)f2bf(a.x) | ((unsigned)f2bf(a.y) << 16);
  unsigned u1 = (unsigned)f2bf(a.z) | ((unsigned)f2bf(a.w) << 16);
  unsigned u2 = (unsigned)f2bf(b.x) | ((unsigned)f2bf(b.y) << 16);
  unsigned u3 = (unsigned)f2bf(b.z) | ((unsigned)f2bf(b.w) << 16);
  uint4 o; o.x = u0; o.y = u1; o.z = u2; o.w = u3;
  *(uint4*)(xb + idx) = o;
}

// ---------------------------------------------------------------------------
// W fp32 [1024][1024] (k-major) -> Wt bf16 [1024][1024] (n-major), 4 weights
// ---------------------------------------------------------------------------
__global__ __launch_bounds__(256)
void transpose_w_kernel(const float* __restrict__ Wa, const float* __restrict__ Wb,
                        const float* __restrict__ Wc, const float* __restrict__ Wd,
                        unsigned short* __restrict__ Wt)
{
  __shared__ float t[64][65];
  const float* W = (blockIdx.z == 0) ? Wa : (blockIdx.z == 1) ? Wb
                 : (blockIdx.z == 2) ? Wc : Wd;
  unsigned short* out = Wt + (size_t)blockIdx.z * 1024 * 1024;
  const int k0 = blockIdx.y * 64;
  const int n0 = blockIdx.x * 64;
  const int tx = threadIdx.x & 63, ty = threadIdx.x >> 6;
#pragma unroll
  for (int r = ty; r < 64; r += 4)
    t[r][tx] = W[(size_t)(k0 + r) * 1024 + n0 + tx];
  __syncthreads();
#pragma unroll
  for (int r = ty; r < 64; r += 4)
    out[(size_t)(n0 + r) * 1024 + k0 + tx] = f2bf(t[tx][r]);
}

// ---------------------------------------------------------------------------
// concat b1||b2 -> bc[2048]
// ---------------------------------------------------------------------------
__global__ __launch_bounds__(256)
void bias_concat_kernel(const float* __restrict__ b1, const float* __restrict__ b2,
                        float* __restrict__ bc)
{
  const int i = blockIdx.x * 256 + threadIdx.x;
  bc[i] = (i < 1024) ? b1[i] : b2[i - 1024];
}

// ---------------------------------------------------------------------------
// row softmax, in place, bf16 rows of 2048 (one block per row)
// ---------------------------------------------------------------------------
__global__ __launch_bounds__(256)
void softmax_kernel(unsigned short* __restrict__ S)
{
  __shared__ float red[8];
  unsigned short* r = S + (size_t)blockIdx.x * 2048;
  const int tid = threadIdx.x, lane = tid & 63, wave = tid >> 6;

  uint4 pk = *(const uint4*)(r + tid * 8);
  const unsigned short* ps = (const unsigned short*)&pk;
  float v[8];
#pragma unroll
  for (int j = 0; j < 8; ++j) v[j] = bf2f(ps[j]);

  float mx = v[0];
#pragma unroll
  for (int j = 1; j < 8; ++j) mx = fmaxf(mx, v[j]);
#pragma unroll
  for (int o = 32; o; o >>= 1) mx = fmaxf(mx, __shfl_xor(mx, o));
  if (lane == 0) red[wave] = mx;
  __syncthreads();
  mx = fmaxf(fmaxf(red[0], red[1]), fmaxf(red[2], red[3]));

  float s = 0.f;
#pragma unroll
  for (int j = 0; j < 8; ++j) { v[j] = __expf(v[j] - mx); s += v[j]; }
#pragma unroll
  for (int o = 32; o; o >>= 1) s += __shfl_xor(s, o);
  if (lane == 0) red[4 + wave] = s;
  __syncthreads();
  const float inv = 1.f / (red[4] + red[5] + red[6] + red[7]);

  unsigned short o8[8];
#pragma unroll
  for (int j = 0; j < 8; ++j) o8[j] = f2bf(v[j] * inv);
  *(uint4*)(r + tid * 8) = *(const uint4*)o8;
}

// ---------------------------------------------------------------------------
extern "C" void kernel_launch(void* const* d_in, const int* in_sizes, int n_in,
                              void* d_out, int out_size, void* d_ws, size_t ws_size,
                              hipStream_t stream)
{
  const float* x  = (const float*)d_in[0];
  const float* W1 = (const float*)d_in[1];
  const float* b1 = (const float*)d_in[2];
  const float* W2 = (const float*)d_in[3];
  const float* b2 = (const float*)d_in[4];
  const float* W3 = (const float*)d_in[5];
  const float* b3 = (const float*)d_in[6];
  const float* W4 = (const float*)d_in[7];
  const float* b4 = (const float*)d_in[8];

  char* ws = (char*)d_ws;
  const size_t MB = 1024 * 1024;
  unsigned short* xb  = (unsigned short*)(ws);             // 16MB
  unsigned short* Wt  = (unsigned short*)(ws + 16 * MB);   // 8MB: [4][1024][1024] (W1t,W2t,W3t,W4t)
  unsigned short* QK  = (unsigned short*)(ws + 24 * MB);   // 32MB: [8192][2048] (Q cols 0-1023, K cols 1024-2047)
  unsigned short* Vt  = (unsigned short*)(ws + 56 * MB);   // 16MB: [4][1024][2048]
  unsigned short* S   = (unsigned short*)(ws + 72 * MB);   // 32MB: [4][2048][2048]
  float*          bc  = (float*)S;                         // 8KB, alias (dead before scores)
  unsigned short* O   = QK;                                // 16MB, alias (QK dead after scores)

  // 1. convert x to bf16; transpose+convert weights; concat b1||b2
  convert_x_kernel<<<4096, 256, 0, stream>>>(x, xb);
  transpose_w_kernel<<<dim3(16, 16, 4), 256, 0, stream>>>(W1, W2, W3, W4, Wt);
  bias_concat_kernel<<<8, 256, 0, stream>>>(b1, b2, bc);

  // 2. fused Q+K projection: QK[8192][2048] = xb @ [W1t;W2t]^T + [b1;b2]
  gemm_bt_kernel<1, false><<<dim3(16, 64, 1), 256, 0, stream>>>(
      xb, Wt, bc, QK, 2048, 1024, 1024, 1024, 2048, 1.f, 0, 0, 0);

  // 3. Vt[z][e][t] = W3t @ xb[z]^T + b3[e]  (bias per row)
  gemm_bt_kernel<2, false><<<dim3(16, 8, 4), 256, 0, stream>>>(
      Wt + 2 * 1048576, xb, b3, Vt, 2048, 1024, 1024, 1024, 2048, 1.f,
      0, 2048L * 1024, 1024L * 2048);

  // 4. scores: S[z] = (Q[z] @ K[z]^T) / 32
  gemm_bt_kernel<0, false><<<dim3(16, 16, 4), 256, 0, stream>>>(
      QK, QK + 1024, nullptr, S, 2048, 1024, 2048, 2048, 2048, 0.03125f,
      2048L * 2048, 2048L * 2048, 2048L * 2048);

  // 5. softmax rows, in place
  softmax_kernel<<<8192, 256, 0, stream>>>(S);

  // 6. O[z] = P[z] @ V[z]  (Bt = Vt[z] as [1024][2048])
  gemm_bt_kernel<0, false><<<dim3(8, 16, 4), 256, 0, stream>>>(
      S, Vt, nullptr, O, 1024, 2048, 2048, 2048, 1024, 1.f,
      2048L * 2048, 1024L * 2048, 2048L * 1024);

  // 7. out = O @ W4t^T + b4  (fp32 out)
  gemm_bt_kernel<1, true><<<dim3(8, 64, 1), 256, 0, stream>>>(
      O, Wt + 3 * 1048576, b4, d_out, 1024, 1024, 1024, 1024, 1024, 1.f,
      0, 0, 0);
}

// Round 3
// 203.893 us; speedup vs baseline: 1.2821x; 1.0966x over previous
//
#include <hip/hip_runtime.h>
#include <hip/hip_bf16.h>

typedef __attribute__((ext_vector_type(4))) float f32x4;
typedef __attribute__((ext_vector_type(8))) short bf16x8;

__device__ __forceinline__ void gload_lds16(const void* g, void* l) {
  __builtin_amdgcn_global_load_lds(
      (const __attribute__((address_space(1))) void*)g,
      (__attribute__((address_space(3))) void*)l, 16, 0, 0);
}

__device__ __forceinline__ unsigned short f2bf(float f) {
  union { float f; unsigned u; } x; x.f = f;
  unsigned r = x.u + 0x7fffu + ((x.u >> 16) & 1u);
  return (unsigned short)(r >> 16);
}

__device__ __forceinline__ float bf2f(unsigned short s) {
  union { unsigned u; float f; } x; x.u = (unsigned)s << 16;
  return x.f;
}

template<int N> __device__ __forceinline__ void vm_wait();
template<> __device__ __forceinline__ void vm_wait<0>() { asm volatile("s_waitcnt vmcnt(0)" ::: "memory"); }
template<> __device__ __forceinline__ void vm_wait<4>() { asm volatile("s_waitcnt vmcnt(4)" ::: "memory"); }
template<> __device__ __forceinline__ void vm_wait<6>() { asm volatile("s_waitcnt vmcnt(6)" ::: "memory"); }

#define BARRIER() asm volatile("s_barrier" ::: "memory")
#define LGKM0()   do { asm volatile("s_waitcnt lgkmcnt(0)" ::: "memory"); \
                       __builtin_amdgcn_sched_barrier(0); } while (0)

// ---------------------------------------------------------------------------
// 256xBN 8-phase double-buffered GEMM: C = alpha * A[M][K] @ Bt[N][K]^T (+bias)
// BIAS_MODE: 0 none, 1 bias[col], 2 bias[row]. 512 threads, BK=64.
// ---------------------------------------------------------------------------
template<int BN, int BIAS_MODE, bool OUT_F32>
__global__ __launch_bounds__(512, 2)
void gemm256(const unsigned short* __restrict__ A,
             const unsigned short* __restrict__ Bt,
             const float* __restrict__ bias,
             void* __restrict__ Cout,
             int N, int K, int lda, int ldb, int ldc, float alpha,
             long sA, long sB, long sC)
{
  constexpr int THREADS = 512;
  constexpr int WN = BN / 64;          // waves along N (4 or 2)
  constexpr int WM = 8 / WN;           // waves along M (2 or 4)
  constexpr int WTM = 256 / WM;        // wave M extent (128 or 64)
  constexpr int M_REP = WTM / 16;      // 8 or 4
  constexpr int MH = M_REP / 2;        // 4 or 2
  constexpr int ABUFE = 256 * 64;      // elements per A buffer
  constexpr int BBUFE = BN * 64;
  constexpr int BBASE = 2 * ABUFE;
  constexpr int LOADS_A = 2;           // loads/thread per A half-tile (128 rows)
  constexpr int LOADS_B = BN / 128;    // loads/thread per B half-tile (BN/2 rows)
  constexpr int VM_STEADY = 2 * LOADS_B + LOADS_A;  // 6 or 4

  __shared__ __attribute__((aligned(16))) unsigned short lds[BBASE + 2 * BBUFE];

  // bijective XCD-chunked swizzle
  const int gx = gridDim.x, gy = gridDim.y;
  const int lid = blockIdx.x + gx * (blockIdx.y + gy * blockIdx.z);
  const int nwg = gx * gy * gridDim.z;
  const int q = nwg >> 3, r = nwg & 7;
  const int xcd = lid & 7, idx = lid >> 3;
  const int nl = (xcd < r ? xcd * (q + 1) : r * (q + 1) + (xcd - r) * q) + idx;
  const int bx = nl % gx, by = (nl / gx) % gy, bz = nl / (gx * gy);

  const int tid = threadIdx.x, wave = tid >> 6, lane = tid & 63;
  const int wr = wave / WN, wc = wave % WN;
  const int fr = lane & 15, fq = lane >> 4, sw = fr & 7;

  A  += (size_t)bz * sA;
  Bt += (size_t)bz * sB;
  const int m0 = by * 256;
  const int n0 = bx * BN;
  const int NT = K >> 6;

  f32x4 acc[M_REP][4] = {};
  bf16x8 a[MH][2], b[4][2];

  // ---- staging (linear LDS dest; XOR-swizzle realized via permuted source)
  auto stageA = [&](int t, int half) {
#pragma unroll
    for (int c = 0; c < LOADS_A; ++c) {
      const int s = c * THREADS + tid;          // 16B chunk index in half-tile
      const int rr = s >> 3;                    // row within half (0..127)
      const int col = ((tid & 7) ^ (rr & 7)) * 8;
      gload_lds16(A + (size_t)(m0 + half * 128 + rr) * lda + t * 64 + col,
                  &lds[(t & 1) * ABUFE + half * (128 * 64) + s * 8]);
    }
  };
  auto stageB = [&](int t, int half) {
#pragma unroll
    for (int c = 0; c < LOADS_B; ++c) {
      const int s = c * THREADS + tid;
      const int rr = s >> 3;
      const int col = ((tid & 7) ^ (rr & 7)) * 8;
      gload_lds16(Bt + (size_t)(n0 + half * (BN / 2) + rr) * ldb + t * 64 + col,
                  &lds[BBASE + (t & 1) * BBUFE + half * ((BN / 2) * 64) + s * 8]);
    }
  };
  // ---- fragment reads (swizzled)
  auto readA = [&](int buf, int mq) {
    const unsigned short* p = &lds[buf * ABUFE];
#pragma unroll
    for (int mm = 0; mm < MH; ++mm)
#pragma unroll
      for (int kk = 0; kk < 2; ++kk)
        a[mm][kk] = *(const bf16x8*)(p + (wr * WTM + mq * (WTM / 2) + mm * 16 + fr) * 64
                                       + ((kk * 4 + fq) ^ sw) * 8);
  };
  auto readB = [&](int buf, int nh) {
    const unsigned short* p = &lds[BBASE + buf * BBUFE];
#pragma unroll
    for (int nn = 0; nn < 2; ++nn)
#pragma unroll
      for (int kk = 0; kk < 2; ++kk)
        b[nh * 2 + nn][kk] = *(const bf16x8*)(p + (wc * 64 + (nh * 2 + nn) * 16 + fr) * 64
                                                + ((kk * 4 + fq) ^ sw) * 8);
  };
  auto mfmaQ = [&](int mq, int nh) {
    __builtin_amdgcn_s_setprio(1);
#pragma unroll
    for (int kk = 0; kk < 2; ++kk)
#pragma unroll
      for (int mm = 0; mm < MH; ++mm)
#pragma unroll
        for (int nn = 0; nn < 2; ++nn)
          acc[mq * MH + mm][nh * 2 + nn] = __builtin_amdgcn_mfma_f32_16x16x32_bf16(
              a[mm][kk], b[nh * 2 + nn][kk], acc[mq * MH + mm][nh * 2 + nn], 0, 0, 0);
    __builtin_amdgcn_s_setprio(0);
  };

  // ---- prologue: tile0 fully, tile1 {B0,B1,A0}
  stageA(0, 0); stageA(0, 1); stageB(0, 0); stageB(0, 1);
  if (NT > 1) { stageB(1, 0); stageB(1, 1); stageA(1, 0); vm_wait<VM_STEADY>(); }
  else        { vm_wait<0>(); }
  BARRIER();

  // ---- main loop: 4 phases per K-tile
  for (int t = 0; t < NT; ++t) {
    const int buf = t & 1;
    // ph1
    readA(buf, 0); readB(buf, 0);
    if (t + 1 < NT) stageA(t + 1, 1);
    BARRIER(); LGKM0();
    mfmaQ(0, 0);
    BARRIER();
    // ph2
    readB(buf, 1);
    BARRIER(); LGKM0();
    mfmaQ(0, 1);
    BARRIER();
    // ph3
    readA(buf, 1);
    if (t + 2 < NT) stageB(t + 2, 0);
    BARRIER(); LGKM0();
    mfmaQ(1, 0);
    BARRIER();
    // ph4
    if (t + 2 < NT) { stageB(t + 2, 1); stageA(t + 2, 0); vm_wait<VM_STEADY>(); }
    else            { vm_wait<0>(); }
    BARRIER(); LGKM0();
    mfmaQ(1, 1);
    BARRIER();
  }

  // ---- epilogue
#pragma unroll
  for (int nn = 0; nn < 4; ++nn) {
    const int col = n0 + wc * 64 + nn * 16 + fr;
    const float bvc = (BIAS_MODE == 1) ? bias[col] : 0.f;
#pragma unroll
    for (int mm = 0; mm < M_REP; ++mm) {
      const int rbase = m0 + wr * WTM + mm * 16 + fq * 4;
#pragma unroll
      for (int j = 0; j < 4; ++j) {
        float v = acc[mm][nn][j] * alpha + bvc;
        if (BIAS_MODE == 2) v += bias[rbase + j];
        const size_t off = (size_t)bz * sC + (size_t)(rbase + j) * ldc + col;
        if (OUT_F32) ((float*)Cout)[off] = v;
        else         ((unsigned short*)Cout)[off] = f2bf(v);
      }
    }
  }
}

// ---------------------------------------------------------------------------
__global__ __launch_bounds__(256)
void convert_x_kernel(const float* __restrict__ x, unsigned short* __restrict__ xb)
{
  const int idx = (blockIdx.x * 256 + threadIdx.x) * 8;
  const float4 a = *(const float4*)(x + idx);
  const float4 b = *(const float4*)(x + idx + 4);
  unsigned u0 = (unsigned)f2bf(a.x) | ((unsigned)f2bf(a.y) << 16);
  unsigned u1 = (unsigned)f2bf(a.z) | ((unsigned)f2bf(a.w) << 16);
  unsigned u2 = (unsigned)f2bf(b.x) | ((unsigned)f2bf(b.y) << 16);
  unsigned u3 = (unsigned)f2bf(b.z) | ((unsigned)f2bf(b.w) << 16);
  uint4 o; o.x = u0; o.y = u1; o.z = u2; o.w = u3;
  *(uint4*)(xb + idx) = o;
}

__global__ __launch_bounds__(256)
void transpose_w_kernel(const float* __restrict__ Wa, const float* __restrict__ Wb,
                        const float* __restrict__ Wc, const float* __restrict__ Wd,
                        unsigned short* __restrict__ Wt)
{
  __shared__ float t[64][65];
  const float* W = (blockIdx.z == 0) ? Wa : (blockIdx.z == 1) ? Wb
                 : (blockIdx.z == 2) ? Wc : Wd;
  unsigned short* out = Wt + (size_t)blockIdx.z * 1024 * 1024;
  const int k0 = blockIdx.y * 64;
  const int n0 = blockIdx.x * 64;
  const int tx = threadIdx.x & 63, ty = threadIdx.x >> 6;
#pragma unroll
  for (int r = ty; r < 64; r += 4)
    t[r][tx] = W[(size_t)(k0 + r) * 1024 + n0 + tx];
  __syncthreads();
#pragma unroll
  for (int r = ty; r < 64; r += 4)
    out[(size_t)(n0 + r) * 1024 + k0 + tx] = f2bf(t[tx][r]);
}

__global__ __launch_bounds__(256)
void bias_concat_kernel(const float* __restrict__ b1, const float* __restrict__ b2,
                        float* __restrict__ bc)
{
  const int i = blockIdx.x * 256 + threadIdx.x;
  bc[i] = (i < 1024) ? b1[i] : b2[i - 1024];
}

__global__ __launch_bounds__(256)
void softmax_kernel(unsigned short* __restrict__ S)
{
  __shared__ float red[8];
  unsigned short* r = S + (size_t)blockIdx.x * 2048;
  const int tid = threadIdx.x, lane = tid & 63, wave = tid >> 6;

  uint4 pk = *(const uint4*)(r + tid * 8);
  const unsigned short* ps = (const unsigned short*)&pk;
  float v[8];
#pragma unroll
  for (int j = 0; j < 8; ++j) v[j] = bf2f(ps[j]);

  float mx = v[0];
#pragma unroll
  for (int j = 1; j < 8; ++j) mx = fmaxf(mx, v[j]);
#pragma unroll
  for (int o = 32; o; o >>= 1) mx = fmaxf(mx, __shfl_xor(mx, o));
  if (lane == 0) red[wave] = mx;
  __syncthreads();
  mx = fmaxf(fmaxf(red[0], red[1]), fmaxf(red[2], red[3]));

  float s = 0.f;
#pragma unroll
  for (int j = 0; j < 8; ++j) { v[j] = __expf(v[j] - mx); s += v[j]; }
#pragma unroll
  for (int o = 32; o; o >>= 1) s += __shfl_xor(s, o);
  if (lane == 0) red[4 + wave] = s;
  __syncthreads();
  const float inv = 1.f / (red[4] + red[5] + red[6] + red[7]);

  unsigned short o8[8];
#pragma unroll
  for (int j = 0; j < 8; ++j) o8[j] = f2bf(v[j] * inv);
  *(uint4*)(r + tid * 8) = *(const uint4*)o8;
}

// ---------------------------------------------------------------------------
extern "C" void kernel_launch(void* const* d_in, const int* in_sizes, int n_in,
                              void* d_out, int out_size, void* d_ws, size_t ws_size,
                              hipStream_t stream)
{
  const float* x  = (const float*)d_in[0];
  const float* W1 = (const float*)d_in[1];
  const float* b1 = (const float*)d_in[2];
  const float* W2 = (const float*)d_in[3];
  const float* b2 = (const float*)d_in[4];
  const float* W3 = (const float*)d_in[5];
  const float* b3 = (const float*)d_in[6];
  const float* W4 = (const float*)d_in[7];
  const float* b4 = (const float*)d_in[8];

  char* ws = (char*)d_ws;
  const size_t MB = 1024 * 1024;
  unsigned short* xb  = (unsigned short*)(ws);             // 16MB
  unsigned short* Wt  = (unsigned short*)(ws + 16 * MB);   // 8MB: [4][1024][1024]
  unsigned short* QK  = (unsigned short*)(ws + 24 * MB);   // 32MB: [8192][2048]
  unsigned short* Vt  = (unsigned short*)(ws + 56 * MB);   // 16MB: [4][1024][2048]
  unsigned short* S   = (unsigned short*)(ws + 72 * MB);   // 32MB: [4][2048][2048]
  float*          bc  = (float*)S;                         // 8KB alias (dead before scores)
  unsigned short* O   = QK;                                // alias (QK dead after scores)

  convert_x_kernel<<<4096, 256, 0, stream>>>(x, xb);
  transpose_w_kernel<<<dim3(16, 16, 4), 256, 0, stream>>>(W1, W2, W3, W4, Wt);
  bias_concat_kernel<<<8, 256, 0, stream>>>(b1, b2, bc);

  // fused Q+K projection: QK = xb @ [W1t;W2t]^T + [b1;b2]   (256 blocks)
  gemm256<256, 1, false><<<dim3(8, 32, 1), 512, 0, stream>>>(
      xb, Wt, bc, QK, 2048, 1024, 1024, 1024, 2048, 1.f, 0, 0, 0);

  // Vt[z] = W3t @ xb[z]^T + b3[row]                         (256 blocks)
  gemm256<128, 2, false><<<dim3(16, 4, 4), 512, 0, stream>>>(
      Wt + 2 * 1048576, xb, b3, Vt, 2048, 1024, 1024, 1024, 2048, 1.f,
      0, 2048L * 1024, 1024L * 2048);

  // scores: S[z] = (Q[z] @ K[z]^T) / 32                     (256 blocks)
  gemm256<256, 0, false><<<dim3(8, 8, 4), 512, 0, stream>>>(
      QK, QK + 1024, nullptr, S, 2048, 1024, 2048, 2048, 2048, 0.03125f,
      2048L * 2048, 2048L * 2048, 2048L * 2048);

  softmax_kernel<<<8192, 256, 0, stream>>>(S);

  // O[z] = P[z] @ V[z]                                      (256 blocks)
  gemm256<128, 0, false><<<dim3(8, 8, 4), 512, 0, stream>>>(
      S, Vt, nullptr, O, 1024, 2048, 2048, 2048, 1024, 1.f,
      2048L * 2048, 1024L * 2048, 2048L * 1024);

  // out = O @ W4t^T + b4  (fp32)                            (256 blocks)
  gemm256<128, 1, true><<<dim3(8, 32, 1), 512, 0, stream>>>(
      O, Wt + 3 * 1048576, b4, d_out, 1024, 1024, 1024, 1024, 1024, 1.f,
      0, 0, 0);
}

// Round 4
// 194.640 us; speedup vs baseline: 1.3431x; 1.0475x over previous
//
#include <hip/hip_runtime.h>
#include <hip/hip_bf16.h>

typedef __attribute__((ext_vector_type(4))) float f32x4;
typedef __attribute__((ext_vector_type(8))) short bf16x8;

__device__ __forceinline__ void gload_lds16(const void* g, void* l) {
  __builtin_amdgcn_global_load_lds(
      (const __attribute__((address_space(1))) void*)g,
      (__attribute__((address_space(3))) void*)l, 16, 0, 0);
}

__device__ __forceinline__ unsigned short f2bf(float f) {
  union { float f; unsigned u; } x; x.f = f;
  unsigned r = x.u + 0x7fffu + ((x.u >> 16) & 1u);
  return (unsigned short)(r >> 16);
}

__device__ __forceinline__ float bf2f(unsigned short s) {
  union { unsigned u; float f; } x; x.u = (unsigned)s << 16;
  return x.f;
}

template<int N> __device__ __forceinline__ void vm_wait();
template<> __device__ __forceinline__ void vm_wait<0>() { asm volatile("s_waitcnt vmcnt(0)" ::: "memory"); }
template<> __device__ __forceinline__ void vm_wait<4>() { asm volatile("s_waitcnt vmcnt(4)" ::: "memory"); }
template<> __device__ __forceinline__ void vm_wait<6>() { asm volatile("s_waitcnt vmcnt(6)" ::: "memory"); }

#define BARRIER() asm volatile("s_barrier" ::: "memory")
#define LGKM0()   do { asm volatile("s_waitcnt lgkmcnt(0)" ::: "memory"); \
                       __builtin_amdgcn_sched_barrier(0); } while (0)

// ---------------------------------------------------------------------------
// 256xBN 8-phase double-buffered GEMM: C = f(alpha * A[M][K] @ Bt[N][K]^T)
// EPI: 0 = alpha only, 1 = +bias[col], 2 = +bias[row],
//      3 = exp(alpha*acc) + atomic per-row sum into rs,
//      4 = acc * rcp(rs[row]).
// 512 threads, BK=64, T1 XCD swizzle, T2 LDS swizzle, T4 counted vmcnt, T5.
// ---------------------------------------------------------------------------
template<int BN, int EPI, bool OUT_F32>
__global__ __launch_bounds__(512, 2)
void gemm256(const unsigned short* __restrict__ A,
             const unsigned short* __restrict__ Bt,
             const float* __restrict__ bias,
             float* __restrict__ rs,
             void* __restrict__ Cout,
             int K, int lda, int ldb, int ldc, float alpha,
             long sA, long sB, long sC)
{
  constexpr int THREADS = 512;
  constexpr int WN = BN / 64;          // waves along N (4 or 2)
  constexpr int WM = 8 / WN;           // waves along M (2 or 4)
  constexpr int WTM = 256 / WM;        // wave M extent (128 or 64)
  constexpr int M_REP = WTM / 16;      // 8 or 4
  constexpr int MH = M_REP / 2;        // 4 or 2
  constexpr int ABUFE = 256 * 64;      // elements per A buffer
  constexpr int BBUFE = BN * 64;
  constexpr int BBASE = 2 * ABUFE;
  constexpr int LOADS_A = 2;           // loads/thread per A half-tile (128 rows)
  constexpr int LOADS_B = BN / 128;    // loads/thread per B half-tile (BN/2 rows)
  constexpr int VM_STEADY = 2 * LOADS_B + LOADS_A;  // 6 or 4

  __shared__ __attribute__((aligned(16))) unsigned short lds[BBASE + 2 * BBUFE];

  // bijective XCD-chunked swizzle
  const int gx = gridDim.x, gy = gridDim.y;
  const int lid = blockIdx.x + gx * (blockIdx.y + gy * blockIdx.z);
  const int nwg = gx * gy * gridDim.z;
  const int q = nwg >> 3, r = nwg & 7;
  const int xcd = lid & 7, idx = lid >> 3;
  const int nl = (xcd < r ? xcd * (q + 1) : r * (q + 1) + (xcd - r) * q) + idx;
  const int bx = nl % gx, by = (nl / gx) % gy, bz = nl / (gx * gy);

  const int tid = threadIdx.x, wave = tid >> 6, lane = tid & 63;
  const int wr = wave / WN, wc = wave % WN;
  const int fr = lane & 15, fq = lane >> 4, sw = fr & 7;

  A  += (size_t)bz * sA;
  Bt += (size_t)bz * sB;
  const int m0 = by * 256;
  const int n0 = bx * BN;
  const int NT = K >> 6;

  f32x4 acc[M_REP][4] = {};
  bf16x8 a[MH][2], b[4][2];

  // ---- staging (linear LDS dest; XOR-swizzle realized via permuted source)
  auto stageA = [&](int t, int half) {
#pragma unroll
    for (int c = 0; c < LOADS_A; ++c) {
      const int s = c * THREADS + tid;          // 16B chunk index in half-tile
      const int rr = s >> 3;                    // row within half (0..127)
      const int col = ((tid & 7) ^ (rr & 7)) * 8;
      gload_lds16(A + (size_t)(m0 + half * 128 + rr) * lda + t * 64 + col,
                  &lds[(t & 1) * ABUFE + half * (128 * 64) + s * 8]);
    }
  };
  auto stageB = [&](int t, int half) {
#pragma unroll
    for (int c = 0; c < LOADS_B; ++c) {
      const int s = c * THREADS + tid;
      const int rr = s >> 3;
      const int col = ((tid & 7) ^ (rr & 7)) * 8;
      gload_lds16(Bt + (size_t)(n0 + half * (BN / 2) + rr) * ldb + t * 64 + col,
                  &lds[BBASE + (t & 1) * BBUFE + half * ((BN / 2) * 64) + s * 8]);
    }
  };
  // ---- fragment reads (swizzled)
  auto readA = [&](int buf, int mq) {
    const unsigned short* p = &lds[buf * ABUFE];
#pragma unroll
    for (int mm = 0; mm < MH; ++mm)
#pragma unroll
      for (int kk = 0; kk < 2; ++kk)
        a[mm][kk] = *(const bf16x8*)(p + (wr * WTM + mq * (WTM / 2) + mm * 16 + fr) * 64
                                       + ((kk * 4 + fq) ^ sw) * 8);
  };
  auto readB = [&](int buf, int nh) {
    const unsigned short* p = &lds[BBASE + buf * BBUFE];
#pragma unroll
    for (int nn = 0; nn < 2; ++nn)
#pragma unroll
      for (int kk = 0; kk < 2; ++kk)
        b[nh * 2 + nn][kk] = *(const bf16x8*)(p + (wc * 64 + (nh * 2 + nn) * 16 + fr) * 64
                                                + ((kk * 4 + fq) ^ sw) * 8);
  };
  auto mfmaQ = [&](int mq, int nh) {
    __builtin_amdgcn_s_setprio(1);
#pragma unroll
    for (int kk = 0; kk < 2; ++kk)
#pragma unroll
      for (int mm = 0; mm < MH; ++mm)
#pragma unroll
        for (int nn = 0; nn < 2; ++nn)
          acc[mq * MH + mm][nh * 2 + nn] = __builtin_amdgcn_mfma_f32_16x16x32_bf16(
              a[mm][kk], b[nh * 2 + nn][kk], acc[mq * MH + mm][nh * 2 + nn], 0, 0, 0);
    __builtin_amdgcn_s_setprio(0);
  };

  // ---- prologue: tile0 fully, tile1 {B0,B1,A0}
  stageA(0, 0); stageA(0, 1); stageB(0, 0); stageB(0, 1);
  if (NT > 1) { stageB(1, 0); stageB(1, 1); stageA(1, 0); vm_wait<VM_STEADY>(); }
  else        { vm_wait<0>(); }
  BARRIER();

  // ---- main loop: 4 phases per K-tile
  for (int t = 0; t < NT; ++t) {
    const int buf = t & 1;
    // ph1
    readA(buf, 0); readB(buf, 0);
    BARRIER(); LGKM0();
    mfmaQ(0, 0);
    BARRIER();
    // ph2
    readB(buf, 1);
    if (t + 1 < NT) stageA(t + 1, 1);
    BARRIER(); LGKM0();
    mfmaQ(0, 1);
    BARRIER();
    // ph3
    readA(buf, 1);
    if (t + 2 < NT) stageB(t + 2, 0);
    BARRIER(); LGKM0();
    mfmaQ(1, 0);
    BARRIER();
    // ph4
    if (t + 2 < NT) { stageB(t + 2, 1); stageA(t + 2, 0); vm_wait<VM_STEADY>(); }
    else            { vm_wait<0>(); }
    BARRIER(); LGKM0();
    mfmaQ(1, 1);
    BARRIER();
  }

  // ---- epilogue (nn innermost: 4 stores covering one 128B row-chunk stay
  //      adjacent -> L2 write combining, avoids partial-line RMW blowup)
  float bvc[4];
  if (EPI == 1) {
#pragma unroll
    for (int nn = 0; nn < 4; ++nn) bvc[nn] = bias[n0 + wc * 64 + nn * 16 + fr];
  }
#pragma unroll
  for (int mm = 0; mm < M_REP; ++mm) {
    const int rbase = m0 + wr * WTM + mm * 16 + fq * 4;
#pragma unroll
    for (int j = 0; j < 4; ++j) {
      const int row = rbase + j;
      float bvr = 0.f, rsc = 1.f;
      if (EPI == 2) bvr = bias[row];
      if (EPI == 4) rsc = __builtin_amdgcn_rcpf(rs[(size_t)bz * 2048 + row]);
      float part = 0.f;
#pragma unroll
      for (int nn = 0; nn < 4; ++nn) {
        const int col = n0 + wc * 64 + nn * 16 + fr;
        float v = acc[mm][nn][j];
        if      (EPI == 1) v = v * alpha + bvc[nn];
        else if (EPI == 2) v = v * alpha + bvr;
        else if (EPI == 3) { v = __expf(v * alpha); part += v; }
        else if (EPI == 4) v = v * rsc;
        else               v = v * alpha;
        const size_t off = (size_t)bz * sC + (size_t)row * ldc + col;
        if (OUT_F32) ((float*)Cout)[off] = v;
        else         ((unsigned short*)Cout)[off] = f2bf(v);
      }
      if (EPI == 3) {
        part += __shfl_xor(part, 1); part += __shfl_xor(part, 2);
        part += __shfl_xor(part, 4); part += __shfl_xor(part, 8);
        if (fr == 0) atomicAdd(rs + (size_t)bz * 2048 + row, part);
      }
    }
  }
}

// ---------------------------------------------------------------------------
__global__ __launch_bounds__(256)
void convert_x_kernel(const float* __restrict__ x, unsigned short* __restrict__ xb)
{
  const int idx = (blockIdx.x * 256 + threadIdx.x) * 8;
  const float4 a = *(const float4*)(x + idx);
  const float4 b = *(const float4*)(x + idx + 4);
  unsigned u0 = (unsigned)f2bf(a.x) | ((unsigned)f2bf(a.y) << 16);
  unsigned u1 = (unsigned)f2bf(a.z) | ((unsigned)f2bf(a.w) << 16);
  unsigned u2 = (unsigned)f2bf(b.x) | ((unsigned)f2bf(b.y) << 16);
  unsigned u3 = (unsigned)f2bf(b.z) | ((unsigned)f2bf(b.w) << 16);
  uint4 o; o.x = u0; o.y = u1; o.z = u2; o.w = u3;
  *(uint4*)(xb + idx) = o;
}

__global__ __launch_bounds__(256)
void transpose_w_kernel(const float* __restrict__ Wa, const float* __restrict__ Wb,
                        const float* __restrict__ Wc, const float* __restrict__ Wd,
                        unsigned short* __restrict__ Wt)
{
  __shared__ float t[64][65];
  const float* W = (blockIdx.z == 0) ? Wa : (blockIdx.z == 1) ? Wb
                 : (blockIdx.z == 2) ? Wc : Wd;
  unsigned short* out = Wt + (size_t)blockIdx.z * 1024 * 1024;
  const int k0 = blockIdx.y * 64;
  const int n0 = blockIdx.x * 64;
  const int tx = threadIdx.x & 63, ty = threadIdx.x >> 6;
#pragma unroll
  for (int r = ty; r < 64; r += 4)
    t[r][tx] = W[(size_t)(k0 + r) * 1024 + n0 + tx];
  __syncthreads();
#pragma unroll
  for (int r = ty; r < 64; r += 4)
    out[(size_t)(n0 + r) * 1024 + k0 + tx] = f2bf(t[tx][r]);
}

__global__ __launch_bounds__(256)
void bias_concat_kernel(const float* __restrict__ b1, const float* __restrict__ b2,
                        float* __restrict__ bc)
{
  const int i = blockIdx.x * 256 + threadIdx.x;
  bc[i] = (i < 1024) ? b1[i] : b2[i - 1024];
}

// ---------------------------------------------------------------------------
extern "C" void kernel_launch(void* const* d_in, const int* in_sizes, int n_in,
                              void* d_out, int out_size, void* d_ws, size_t ws_size,
                              hipStream_t stream)
{
  const float* x  = (const float*)d_in[0];
  const float* W1 = (const float*)d_in[1];
  const float* b1 = (const float*)d_in[2];
  const float* W2 = (const float*)d_in[3];
  const float* b2 = (const float*)d_in[4];
  const float* W3 = (const float*)d_in[5];
  const float* b3 = (const float*)d_in[6];
  const float* W4 = (const float*)d_in[7];
  const float* b4 = (const float*)d_in[8];

  char* ws = (char*)d_ws;
  const size_t MB = 1024 * 1024;
  unsigned short* xb  = (unsigned short*)(ws);             // 16MB (dead after projections)
  unsigned short* Wt  = (unsigned short*)(ws + 16 * MB);   // 8MB: [4][1024][1024]
  unsigned short* QK  = (unsigned short*)(ws + 24 * MB);   // 32MB: [8192][2048]
  unsigned short* Vt  = (unsigned short*)(ws + 56 * MB);   // 16MB: [4][1024][2048]
  unsigned short* S   = (unsigned short*)(ws + 72 * MB);   // 32MB: [4][2048][2048] (exp values)
  float*          bc  = (float*)S;                         // 8KB alias (dead before scores)
  float*          rsum = (float*)ws;                       // 32KB alias xb (dead after projections)
  unsigned short* O   = QK;                                // alias (QK dead after scores)

  convert_x_kernel<<<4096, 256, 0, stream>>>(x, xb);
  transpose_w_kernel<<<dim3(16, 16, 4), 256, 0, stream>>>(W1, W2, W3, W4, Wt);
  bias_concat_kernel<<<8, 256, 0, stream>>>(b1, b2, bc);

  // fused Q+K projection: QK = xb @ [W1t;W2t]^T + [b1;b2]   (256 blocks)
  gemm256<256, 1, false><<<dim3(8, 32, 1), 512, 0, stream>>>(
      xb, Wt, bc, nullptr, QK, 1024, 1024, 1024, 2048, 1.f, 0, 0, 0);

  // Vt[z] = W3t @ xb[z]^T + b3[row]                         (256 blocks)
  gemm256<128, 2, false><<<dim3(16, 4, 4), 512, 0, stream>>>(
      Wt + 2 * 1048576, xb, b3, nullptr, Vt, 1024, 1024, 1024, 2048, 1.f,
      0, 2048L * 1024, 1024L * 2048);

  // zero per-row exp-sums (xb region is dead from here on; in-order stream)
  hipMemsetAsync(rsum, 0, 4 * 2048 * sizeof(float), stream);

  // scores: S[z] = exp((Q[z] @ K[z]^T) / 32), rowsum -> rsum  (256 blocks)
  gemm256<256, 3, false><<<dim3(8, 8, 4), 512, 0, stream>>>(
      QK, QK + 1024, nullptr, rsum, S, 1024, 2048, 2048, 2048, 0.03125f,
      2048L * 2048, 2048L * 2048, 2048L * 2048);

  // O[z] = (S[z] @ V[z]) * rcp(rsum[row])                   (256 blocks)
  gemm256<128, 4, false><<<dim3(8, 8, 4), 512, 0, stream>>>(
      S, Vt, nullptr, rsum, O, 2048, 2048, 2048, 1024, 1.f,
      2048L * 2048, 1024L * 2048, 2048L * 1024);

  // out = O @ W4t^T + b4  (fp32)                            (256 blocks)
  gemm256<128, 1, true><<<dim3(8, 32, 1), 512, 0, stream>>>(
      O, Wt + 3 * 1048576, b4, nullptr, d_out, 1024, 1024, 1024, 1024, 1.f,
      0, 0, 0);
}